// Round 3
// baseline (211.493 us; speedup 1.0000x reference)
//
#include <hip/hip_runtime.h>
#include <hip/hip_bf16.h>
#include <cstdint>

typedef __attribute__((ext_vector_type(8))) short short8;
typedef __attribute__((ext_vector_type(16))) float f32x16;

// Problem constants (B, N, D, H) = (256, 100000, 512, 2048)
constexpr int M   = 256;
constexpr int NTB = 100000;
constexpr int D   = 512;
constexpr int H   = 2048;

constexpr int BROWS = 128;                        // table rows per dist block
constexpr int NBLK  = (NTB + BROWS - 1) / BROWS;  // 782
constexpr float EPS_MARGIN = 4.0f;                // ~44 sigma of hi-only bf16 dot error

// ---- ws layout (bytes) ----
constexpr size_t WS_CODES_HI = 0;                                   // 256*512 bf16 frag-ordered
constexpr size_t WS_KEYS     = 262144;                              // [M][NBLK] u64
constexpr size_t WS_IDX      = WS_KEYS + (size_t)M * NBLK * 8;      // 256 u32
constexpr size_t WS_H1       = WS_IDX + 1024;                       // 256*2048 f32

// bf16 helpers (RNE)
__device__ inline unsigned short f2bf_rne(float x) {
  unsigned u = __float_as_uint(x);
  u += 0x7fffu + ((u >> 16) & 1u);
  return (unsigned short)(u >> 16);
}
__device__ inline unsigned long long packkey(float s, unsigned n) {
  unsigned u = __float_as_uint(s);
  u = (u & 0x80000000u) ? ~u : (u | 0x80000000u);  // order-preserving
  return ((unsigned long long)u << 32) | n;
}
__device__ inline float unpackf(unsigned u) {
  u = (u & 0x80000000u) ? (u & 0x7fffffffu) : ~u;
  return __uint_as_float(u);
}
__device__ inline unsigned long long u64min(unsigned long long a, unsigned long long b) {
  return a < b ? a : b;
}

// ---------------- codes -> frag-ordered bf16 hi ----------------
// layout: query-group g=q>>5, k16-step s=k>>4:
//   element (lane = (q&31) | ((k>>3)&1)<<5, j = k&7) at ((g*32+s)*64+lane)*8+j
__global__ __launch_bounds__(256) void convert_codes_kernel(
    const float* __restrict__ codes, unsigned short* __restrict__ chi)
{
  const int i = blockIdx.x * 256 + threadIdx.x;  // 0 .. 256*512-1
  const int q = i >> 9, k = i & 511;
  const int g = q >> 5, s = k >> 4;
  const int lane = (q & 31) | (((k >> 3) & 1) << 5);
  const int j = k & 7;
  chi[((size_t)(g * 32 + s) * 64 + (size_t)lane) * 8 + j] = f2bf_rne(codes[i]);
}

// ---------------- fused bf16-hi MFMA dist + per-block argmin ----------------
__global__ __launch_bounds__(512) void dist_mfma_kernel(
    const float* __restrict__ table,
    const unsigned short* __restrict__ chi,
    unsigned long long* __restrict__ keys)
{
  __shared__ short8 AsH[2][4][2][64];   // [buf][msub32][k16][lane]  = 16 KB
  __shared__ float csq_s[BROWS];
  __shared__ unsigned long long mrg[4][64];

  const int t    = threadIdx.x;
  const int lane = t & 63;
  const int w    = t >> 6;       // wave 0..7
  const int wr   = w >> 2;       // row-wave 0..1
  const int wc   = w & 3;        // col-wave 0..3
  const int blk  = blockIdx.x;

  // staging: 4 threads per row, 8 consecutive k each
  const int srow = t >> 2;
  const int sk   = (t & 3) * 8;
  const int grow = min(blk * BROWS + srow, NTB - 1);
  const float* gsrc = table + (size_t)grow * D + sk;
  const int msub_w = srow >> 5;
  const int s_w    = sk >> 4;
  const int lpos   = (((sk >> 3) & 1) << 5) | (srow & 31);

  // B (codes-hi) frag pointers, direct from global (L2-resident, pre-swizzled)
  const unsigned short* bhp[2];
  #pragma unroll
  for (int nt = 0; nt < 2; ++nt)
    bhp[nt] = chi + (size_t)(wc * 2 + nt) * 16384 + (size_t)lane * 8;

  f32x16 acc[2][2];
  #pragma unroll
  for (int a = 0; a < 2; ++a)
    #pragma unroll
    for (int b = 0; b < 2; ++b)
      #pragma unroll
      for (int r = 0; r < 16; ++r) acc[a][b][r] = 0.f;

  float csq = 0.f;
  float4 p0, p1;

  p0 = *(const float4*)(gsrc);
  p1 = *(const float4*)(gsrc + 4);
  {
    float xs[8] = {p0.x,p0.y,p0.z,p0.w,p1.x,p1.y,p1.z,p1.w};
    short8 vh;
    #pragma unroll
    for (int j = 0; j < 8; ++j) {
      csq += xs[j] * xs[j];
      vh[j] = (short)f2bf_rne(xs[j]);
    }
    AsH[0][msub_w][s_w][lpos] = vh;
  }
  __syncthreads();

  for (int kt = 0; kt < 16; ++kt) {
    const int cur = kt & 1;
    if (kt < 15) {  // reg prefetch of next tile
      p0 = *(const float4*)(gsrc + (kt + 1) * 32);
      p1 = *(const float4*)(gsrc + (kt + 1) * 32 + 4);
    }
    #pragma unroll
    for (int s = 0; s < 2; ++s) {
      const int sg = kt * 2 + s;
      short8 aH[2], bH[2];
      #pragma unroll
      for (int mt = 0; mt < 2; ++mt) aH[mt] = AsH[cur][wr * 2 + mt][s][lane];
      #pragma unroll
      for (int nt = 0; nt < 2; ++nt) bH[nt] = *(const short8*)(bhp[nt] + (size_t)sg * 512);
      #pragma unroll
      for (int mt = 0; mt < 2; ++mt)
        #pragma unroll
        for (int nt = 0; nt < 2; ++nt)
          acc[mt][nt] = __builtin_amdgcn_mfma_f32_32x32x16_bf16(aH[mt], bH[nt], acc[mt][nt], 0, 0, 0);
    }
    if (kt < 15) {
      float xs[8] = {p0.x,p0.y,p0.z,p0.w,p1.x,p1.y,p1.z,p1.w};
      short8 vh;
      #pragma unroll
      for (int j = 0; j < 8; ++j) {
        csq += xs[j] * xs[j];
        vh[j] = (short)f2bf_rne(xs[j]);
      }
      AsH[cur ^ 1][msub_w][s_w][lpos] = vh;
    }
    __syncthreads();
  }

  // finalize exact f32 c_sq (4 staging lanes per row)
  csq += __shfl_xor(csq, 1);
  csq += __shfl_xor(csq, 2);
  if ((t & 3) == 0) csq_s[srow] = csq;
  __syncthreads();

  // per-query argmin of score = c_sq - 2*dot  (x_sq const per query; sqrt monotone)
  unsigned long long bestq[2];
  #pragma unroll
  for (int nt = 0; nt < 2; ++nt) {
    unsigned long long best = ~0ull;
    #pragma unroll
    for (int mt = 0; mt < 2; ++mt) {
      #pragma unroll
      for (int r = 0; r < 16; ++r) {
        const int lrow = wr * 64 + mt * 32 + (r & 3) + ((r >> 2) * 8) + ((lane >> 5) * 4);
        const int gr = blk * BROWS + lrow;
        if (gr < NTB) {
          const float sc = csq_s[lrow] - 2.f * acc[mt][nt][r];
          best = u64min(best, packkey(sc, (unsigned)gr));
        }
      }
    }
    best = u64min(best, __shfl_xor(best, 32));
    bestq[nt] = best;
  }
  if (wr == 1 && lane < 32) {
    mrg[wc][lane]      = bestq[0];
    mrg[wc][32 + lane] = bestq[1];
  }
  __syncthreads();
  if (wr == 0 && lane < 32) {
    #pragma unroll
    for (int nt = 0; nt < 2; ++nt) {
      const unsigned long long b = u64min(bestq[nt], mrg[wc][nt * 32 + lane]);
      const int q = wc * 64 + nt * 32 + lane;
      keys[(size_t)q * NBLK + blk] = b;
    }
  }
}

// ---------------- merge per-block minima + margin rescue (exact f32) ----------------
__global__ __launch_bounds__(256) void merge_rescore_kernel(
    const unsigned long long* __restrict__ keys,
    const float* __restrict__ codes, const float* __restrict__ table,
    unsigned* __restrict__ out_idx)
{
  __shared__ unsigned long long wmin[4];
  __shared__ unsigned long long bestkey_s;
  __shared__ int cand[16];
  __shared__ int ncand;
  __shared__ float redbuf[4];
  __shared__ float bestv_s;
  __shared__ int   besti_s;

  const int q = blockIdx.x, t = threadIdx.x;
  const unsigned long long* row = keys + (size_t)q * NBLK;

  unsigned long long lb = ~0ull;
  for (int i = t; i < NBLK; i += 256) lb = u64min(lb, row[i]);
  #pragma unroll
  for (int off = 1; off < 64; off <<= 1) lb = u64min(lb, __shfl_xor(lb, off));
  if ((t & 63) == 0) wmin[t >> 6] = lb;
  __syncthreads();
  if (t == 0) {
    unsigned long long b = u64min(u64min(wmin[0], wmin[1]), u64min(wmin[2], wmin[3]));
    bestkey_s = b;
    cand[0] = (int)(b & 0xffffffffu);
    ncand = 1;
  }
  __syncthreads();
  const unsigned long long bk = bestkey_s;
  const float thr = unpackf((unsigned)(bk >> 32)) + EPS_MARGIN;
  for (int i = t; i < NBLK; i += 256) {
    unsigned long long v = row[i];
    if (v != bk && unpackf((unsigned)(v >> 32)) <= thr) {
      int p = atomicAdd(&ncand, 1);
      if (p < 16) cand[p] = (int)(v & 0xffffffffu);
    }
  }
  __syncthreads();
  const int nc = min(ncand, 16);
  if (nc == 1) {
    if (t == 0) out_idx[q] = (unsigned)cand[0];
    return;
  }
  if (t == 0) { bestv_s = INFINITY; besti_s = 0x7fffffff; }
  __syncthreads();
  for (int c = 0; c < nc; ++c) {
    const int n = cand[c];
    const float* crow = table + (size_t)n * D;
    const float* xrow = codes + (size_t)q * D;
    float part = 0.f;
    for (int d = t; d < D; d += 256) part += crow[d] * crow[d] - 2.f * xrow[d] * crow[d];
    #pragma unroll
    for (int off = 1; off < 64; off <<= 1) part += __shfl_xor(part, off);
    if ((t & 63) == 0) redbuf[t >> 6] = part;
    __syncthreads();
    if (t == 0) {
      float tot = redbuf[0] + redbuf[1] + redbuf[2] + redbuf[3];
      if (tot < bestv_s || (tot == bestv_s && n < besti_s)) { bestv_s = tot; besti_s = n; }
    }
    __syncthreads();
  }
  if (t == 0) out_idx[q] = (unsigned)besti_s;
}

// ---------------- Kernel B1: h1 = relu(gather(table, idx) @ w1 + b1) --------
constexpr int BM2 = 64, BN2 = 64, BK2 = 16;

__global__ __launch_bounds__(256) void mlp1_kernel(
    const unsigned* __restrict__ final_idx,
    const float* __restrict__ table,
    const float* __restrict__ w1, const float* __restrict__ b1,
    float* __restrict__ h1)
{
  __shared__ float As[BK2][BM2];
  __shared__ float Bs[BK2][BN2];
  __shared__ unsigned idx_s[BM2];

  const int t  = threadIdx.x;
  const int tx = t & 15, ty = t >> 4;
  const int h0 = blockIdx.x * BN2;
  const int m0 = blockIdx.y * BM2;

  if (t < BM2) idx_s[t] = final_idx[m0 + t];
  __syncthreads();

  float acc[4][4] = {{0.f}};
  const int mr = t >> 2, c4 = (t & 3) * 4;
  const int dd = t >> 4, cb = (t & 15) * 4;

  for (int kt = 0; kt < D / BK2; ++kt) {
    const int k0 = kt * BK2;
    float4 av = *(const float4*)(table + (size_t)idx_s[mr] * D + k0 + c4);
    float4 bv = *(const float4*)(w1 + (size_t)(k0 + dd) * H + h0 + cb);
    __syncthreads();
    {
      float a[4] = {av.x, av.y, av.z, av.w};
      #pragma unroll
      for (int j = 0; j < 4; ++j) As[c4 + j][mr] = a[j];
    }
    *(float4*)&Bs[dd][cb] = bv;
    __syncthreads();
    #pragma unroll
    for (int kk = 0; kk < BK2; ++kk) {
      float4 a4 = *(const float4*)&As[kk][ty * 4];
      float4 b4 = *(const float4*)&Bs[kk][tx * 4];
      float a[4] = {a4.x,a4.y,a4.z,a4.w}, b[4] = {b4.x,b4.y,b4.z,b4.w};
      #pragma unroll
      for (int i = 0; i < 4; ++i)
        #pragma unroll
        for (int j = 0; j < 4; ++j) acc[i][j] += a[i] * b[j];
    }
  }

  #pragma unroll
  for (int i = 0; i < 4; ++i) {
    const int m = m0 + ty * 4 + i;
    float v0 = acc[i][0] + b1[h0 + tx * 4 + 0];
    float v1 = acc[i][1] + b1[h0 + tx * 4 + 1];
    float v2 = acc[i][2] + b1[h0 + tx * 4 + 2];
    float v3 = acc[i][3] + b1[h0 + tx * 4 + 3];
    float4 o;
    o.x = v0 > 0.f ? v0 : 0.f;
    o.y = v1 > 0.f ? v1 : 0.f;
    o.z = v2 > 0.f ? v2 : 0.f;
    o.w = v3 > 0.f ? v3 : 0.f;
    *(float4*)(h1 + (size_t)m * H + h0 + tx * 4) = o;
  }
}

// ---------------- Kernel B2: [mu|logstd] = h1 @ [w2u|w2s] + bias ----------
__global__ __launch_bounds__(256) void mlp2_kernel(
    const float* __restrict__ h1,
    const float* __restrict__ w2u, const float* __restrict__ w2s,
    const float* __restrict__ b2u, const float* __restrict__ b2s,
    float* __restrict__ out)
{
  __shared__ float As[BK2][BM2];
  __shared__ float Bs[BK2][BN2];

  const int t  = threadIdx.x;
  const int tx = t & 15, ty = t >> 4;
  const int n0 = blockIdx.x * BN2;           // over [w2u|w2s] concat (2*D wide)
  const int m0 = blockIdx.y * BM2;

  const float* Wn = (n0 < D) ? w2u : w2s;
  const float* bn = (n0 < D) ? b2u : b2s;
  const int col0 = n0 & (D - 1);

  float acc[4][4] = {{0.f}};
  const int mr = t >> 2, c4 = (t & 3) * 4;
  const int dd = t >> 4, cb = (t & 15) * 4;

  for (int kt = 0; kt < H / BK2; ++kt) {
    const int k = kt * BK2;
    float4 av = *(const float4*)(h1 + (size_t)(m0 + mr) * H + k + c4);
    float4 bv = *(const float4*)(Wn + (size_t)(k + dd) * D + col0 + cb);
    __syncthreads();
    {
      float a[4] = {av.x, av.y, av.z, av.w};
      #pragma unroll
      for (int j = 0; j < 4; ++j) As[c4 + j][mr] = a[j];
    }
    *(float4*)&Bs[dd][cb] = bv;
    __syncthreads();
    #pragma unroll
    for (int kk = 0; kk < BK2; ++kk) {
      float4 a4 = *(const float4*)&As[kk][ty * 4];
      float4 b4 = *(const float4*)&Bs[kk][tx * 4];
      float a[4] = {a4.x,a4.y,a4.z,a4.w}, b[4] = {b4.x,b4.y,b4.z,b4.w};
      #pragma unroll
      for (int i = 0; i < 4; ++i)
        #pragma unroll
        for (int j = 0; j < 4; ++j) acc[i][j] += a[i] * b[j];
    }
  }

  #pragma unroll
  for (int i = 0; i < 4; ++i) {
    const int m = m0 + ty * 4 + i;
    const int c = col0 + tx * 4;
    float4 o;
    o.x = acc[i][0] + bn[c + 0];
    o.y = acc[i][1] + bn[c + 1];
    o.z = acc[i][2] + bn[c + 2];
    o.w = acc[i][3] + bn[c + 3];
    float* dst = (n0 < D) ? (out + (size_t)m * D + c)
                          : (out + (size_t)(M * D) + (size_t)m * D + c);
    *(float4*)dst = o;
  }
}

extern "C" void kernel_launch(void* const* d_in, const int* in_sizes, int n_in,
                              void* d_out, int out_size, void* d_ws, size_t ws_size,
                              hipStream_t stream)
{
  const float* codes = (const float*)d_in[0];
  const float* table = (const float*)d_in[1];
  const float* w1    = (const float*)d_in[2];
  const float* b1    = (const float*)d_in[3];
  const float* w2u   = (const float*)d_in[4];
  const float* b2u   = (const float*)d_in[5];
  const float* w2s   = (const float*)d_in[6];
  const float* b2s   = (const float*)d_in[7];
  float* out = (float*)d_out;

  unsigned short* chi = (unsigned short*)((char*)d_ws + WS_CODES_HI);
  unsigned long long* keys = (unsigned long long*)((char*)d_ws + WS_KEYS);
  unsigned* final_idx = (unsigned*)((char*)d_ws + WS_IDX);
  float* h1 = (float*)((char*)d_ws + WS_H1);

  convert_codes_kernel<<<(M * D) / 256, 256, 0, stream>>>(codes, chi);

  dist_mfma_kernel<<<NBLK, 512, 0, stream>>>(table, chi, keys);

  merge_rescore_kernel<<<M, 256, 0, stream>>>(keys, codes, table, final_idx);

  dim3 gB1(H / BN2, M / BM2);
  mlp1_kernel<<<gB1, 256, 0, stream>>>(final_idx, table, w1, b1, h1);

  dim3 gB2((2 * D) / BN2, M / BM2);
  mlp2_kernel<<<gB2, 256, 0, stream>>>(h1, w2u, w2s, b2u, b2s, out);
}

// Round 4
// 143.247 us; speedup vs baseline: 1.4764x; 1.4764x over previous
//
#include <hip/hip_runtime.h>
#include <hip/hip_bf16.h>
#include <cstdint>

typedef __attribute__((ext_vector_type(8))) short short8;
typedef __attribute__((ext_vector_type(16))) float f32x16;

// Problem constants (B, N, D, H) = (256, 100000, 512, 2048)
constexpr int M   = 256;
constexpr int NTB = 100000;
constexpr int D   = 512;
constexpr int H   = 2048;

constexpr int BROWS = 128;                        // table rows per dist block
constexpr int NBLK  = (NTB + BROWS - 1) / BROWS;  // 782
constexpr float EPS_MARGIN = 4.0f;                // ~44 sigma of hi-only bf16 dot error

// ---- ws layout (bytes) ----
constexpr size_t WS_CODES_HI = 0;                                   // 256*512 bf16 frag-ordered
constexpr size_t WS_KEYS     = 262144;                              // [M][NBLK] u64
constexpr size_t WS_IDX      = WS_KEYS + (size_t)M * NBLK * 8;      // 256 u32
constexpr size_t WS_H1       = WS_IDX + 1024;                       // 256*2048 f32

// bf16 helpers (RNE)
__device__ inline unsigned short f2bf_rne(float x) {
  unsigned u = __float_as_uint(x);
  u += 0x7fffu + ((u >> 16) & 1u);
  return (unsigned short)(u >> 16);
}
__device__ inline unsigned long long packkey(float s, unsigned n) {
  unsigned u = __float_as_uint(s);
  u = (u & 0x80000000u) ? ~u : (u | 0x80000000u);  // order-preserving
  return ((unsigned long long)u << 32) | n;
}
__device__ inline float unpackf(unsigned u) {
  u = (u & 0x80000000u) ? (u & 0x7fffffffu) : ~u;
  return __uint_as_float(u);
}
__device__ inline unsigned long long u64min(unsigned long long a, unsigned long long b) {
  return a < b ? a : b;
}

// ---------------- codes -> frag-ordered bf16 hi ----------------
__global__ __launch_bounds__(256) void convert_codes_kernel(
    const float* __restrict__ codes, unsigned short* __restrict__ chi)
{
  const int i = blockIdx.x * 256 + threadIdx.x;  // 0 .. 256*512-1
  const int q = i >> 9, k = i & 511;
  const int g = q >> 5, s = k >> 4;
  const int lane = (q & 31) | (((k >> 3) & 1) << 5);
  const int j = k & 7;
  chi[((size_t)(g * 32 + s) * 64 + (size_t)lane) * 8 + j] = f2bf_rne(codes[i]);
}

// ---------------- fused bf16-hi MFMA dist + per-block argmin ----------------
__global__ __launch_bounds__(512) void dist_mfma_kernel(
    const float* __restrict__ table,
    const unsigned short* __restrict__ chi,
    unsigned long long* __restrict__ keys)
{
  __shared__ short8 AsH[2][4][2][64];   // [buf][msub32][k16][lane]  = 16 KB
  __shared__ float csq_s[BROWS];
  __shared__ unsigned long long mrg[4][64];

  const int t    = threadIdx.x;
  const int lane = t & 63;
  const int w    = t >> 6;
  const int wr   = w >> 2;
  const int wc   = w & 3;
  const int blk  = blockIdx.x;

  const int srow = t >> 2;
  const int sk   = (t & 3) * 8;
  const int grow = min(blk * BROWS + srow, NTB - 1);
  const float* gsrc = table + (size_t)grow * D + sk;
  const int msub_w = srow >> 5;
  const int s_w    = sk >> 4;
  const int lpos   = (((sk >> 3) & 1) << 5) | (srow & 31);

  const unsigned short* bhp[2];
  #pragma unroll
  for (int nt = 0; nt < 2; ++nt)
    bhp[nt] = chi + (size_t)(wc * 2 + nt) * 16384 + (size_t)lane * 8;

  f32x16 acc[2][2];
  #pragma unroll
  for (int a = 0; a < 2; ++a)
    #pragma unroll
    for (int b = 0; b < 2; ++b)
      #pragma unroll
      for (int r = 0; r < 16; ++r) acc[a][b][r] = 0.f;

  float csq = 0.f;
  float4 p0, p1;

  p0 = *(const float4*)(gsrc);
  p1 = *(const float4*)(gsrc + 4);
  {
    float xs[8] = {p0.x,p0.y,p0.z,p0.w,p1.x,p1.y,p1.z,p1.w};
    short8 vh;
    #pragma unroll
    for (int j = 0; j < 8; ++j) {
      csq += xs[j] * xs[j];
      vh[j] = (short)f2bf_rne(xs[j]);
    }
    AsH[0][msub_w][s_w][lpos] = vh;
  }
  __syncthreads();

  for (int kt = 0; kt < 16; ++kt) {
    const int cur = kt & 1;
    if (kt < 15) {
      p0 = *(const float4*)(gsrc + (kt + 1) * 32);
      p1 = *(const float4*)(gsrc + (kt + 1) * 32 + 4);
    }
    #pragma unroll
    for (int s = 0; s < 2; ++s) {
      const int sg = kt * 2 + s;
      short8 aH[2], bH[2];
      #pragma unroll
      for (int mt = 0; mt < 2; ++mt) aH[mt] = AsH[cur][wr * 2 + mt][s][lane];
      #pragma unroll
      for (int nt = 0; nt < 2; ++nt) bH[nt] = *(const short8*)(bhp[nt] + (size_t)sg * 512);
      #pragma unroll
      for (int mt = 0; mt < 2; ++mt)
        #pragma unroll
        for (int nt = 0; nt < 2; ++nt)
          acc[mt][nt] = __builtin_amdgcn_mfma_f32_32x32x16_bf16(aH[mt], bH[nt], acc[mt][nt], 0, 0, 0);
    }
    if (kt < 15) {
      float xs[8] = {p0.x,p0.y,p0.z,p0.w,p1.x,p1.y,p1.z,p1.w};
      short8 vh;
      #pragma unroll
      for (int j = 0; j < 8; ++j) {
        csq += xs[j] * xs[j];
        vh[j] = (short)f2bf_rne(xs[j]);
      }
      AsH[cur ^ 1][msub_w][s_w][lpos] = vh;
    }
    __syncthreads();
  }

  csq += __shfl_xor(csq, 1);
  csq += __shfl_xor(csq, 2);
  if ((t & 3) == 0) csq_s[srow] = csq;
  __syncthreads();

  unsigned long long bestq[2];
  #pragma unroll
  for (int nt = 0; nt < 2; ++nt) {
    unsigned long long best = ~0ull;
    #pragma unroll
    for (int mt = 0; mt < 2; ++mt) {
      #pragma unroll
      for (int r = 0; r < 16; ++r) {
        const int lrow = wr * 64 + mt * 32 + (r & 3) + ((r >> 2) * 8) + ((lane >> 5) * 4);
        const int gr = blk * BROWS + lrow;
        if (gr < NTB) {
          const float sc = csq_s[lrow] - 2.f * acc[mt][nt][r];
          best = u64min(best, packkey(sc, (unsigned)gr));
        }
      }
    }
    best = u64min(best, __shfl_xor(best, 32));
    bestq[nt] = best;
  }
  if (wr == 1 && lane < 32) {
    mrg[wc][lane]      = bestq[0];
    mrg[wc][32 + lane] = bestq[1];
  }
  __syncthreads();
  if (wr == 0 && lane < 32) {
    #pragma unroll
    for (int nt = 0; nt < 2; ++nt) {
      const unsigned long long b = u64min(bestq[nt], mrg[wc][nt * 32 + lane]);
      const int q = wc * 64 + nt * 32 + lane;
      keys[(size_t)q * NBLK + blk] = b;
    }
  }
}

// ---------------- merge per-block minima + margin rescue (exact f32) ----------------
__global__ __launch_bounds__(256) void merge_rescore_kernel(
    const unsigned long long* __restrict__ keys,
    const float* __restrict__ codes, const float* __restrict__ table,
    unsigned* __restrict__ out_idx)
{
  __shared__ unsigned long long wmin[4];
  __shared__ unsigned long long bestkey_s;
  __shared__ int cand[16];
  __shared__ int ncand;
  __shared__ float redbuf[4];
  __shared__ float bestv_s;
  __shared__ int   besti_s;

  const int q = blockIdx.x, t = threadIdx.x;
  const unsigned long long* row = keys + (size_t)q * NBLK;

  unsigned long long lb = ~0ull;
  for (int i = t; i < NBLK; i += 256) lb = u64min(lb, row[i]);
  #pragma unroll
  for (int off = 1; off < 64; off <<= 1) lb = u64min(lb, __shfl_xor(lb, off));
  if ((t & 63) == 0) wmin[t >> 6] = lb;
  __syncthreads();
  if (t == 0) {
    unsigned long long b = u64min(u64min(wmin[0], wmin[1]), u64min(wmin[2], wmin[3]));
    bestkey_s = b;
    cand[0] = (int)(b & 0xffffffffu);
    ncand = 1;
  }
  __syncthreads();
  const unsigned long long bk = bestkey_s;
  const float thr = unpackf((unsigned)(bk >> 32)) + EPS_MARGIN;
  for (int i = t; i < NBLK; i += 256) {
    unsigned long long v = row[i];
    if (v != bk && unpackf((unsigned)(v >> 32)) <= thr) {
      int p = atomicAdd(&ncand, 1);
      if (p < 16) cand[p] = (int)(v & 0xffffffffu);
    }
  }
  __syncthreads();
  const int nc = min(ncand, 16);
  if (nc == 1) {
    if (t == 0) out_idx[q] = (unsigned)cand[0];
    return;
  }
  if (t == 0) { bestv_s = INFINITY; besti_s = 0x7fffffff; }
  __syncthreads();
  for (int c = 0; c < nc; ++c) {
    const int n = cand[c];
    const float* crow = table + (size_t)n * D;
    const float* xrow = codes + (size_t)q * D;
    float part = 0.f;
    for (int d = t; d < D; d += 256) part += crow[d] * crow[d] - 2.f * xrow[d] * crow[d];
    #pragma unroll
    for (int off = 1; off < 64; off <<= 1) part += __shfl_xor(part, off);
    if ((t & 63) == 0) redbuf[t >> 6] = part;
    __syncthreads();
    if (t == 0) {
      float tot = redbuf[0] + redbuf[1] + redbuf[2] + redbuf[3];
      if (tot < bestv_s || (tot == bestv_s && n < besti_s)) { bestv_s = tot; besti_s = n; }
    }
    __syncthreads();
  }
  if (t == 0) out_idx[q] = (unsigned)besti_s;
}

// ---------------- Kernel B1: h1 = relu(gather(table, idx) @ w1 + b1) --------
// 64x64 tile, BK=16, double-buffered LDS + register prefetch (1 barrier/iter)
constexpr int BM2 = 64, BN2 = 64, BK2 = 16;

__global__ __launch_bounds__(256) void mlp1_kernel(
    const unsigned* __restrict__ final_idx,
    const float* __restrict__ table,
    const float* __restrict__ w1, const float* __restrict__ b1,
    float* __restrict__ h1)
{
  __shared__ float As[2][BK2][BM2];
  __shared__ float Bs[2][BK2][BN2];
  __shared__ unsigned idx_s[BM2];

  const int t  = threadIdx.x;
  const int tx = t & 15, ty = t >> 4;
  const int h0 = blockIdx.x * BN2;
  const int m0 = blockIdx.y * BM2;

  if (t < BM2) idx_s[t] = final_idx[m0 + t];
  __syncthreads();

  const int mr = t >> 2, c4 = (t & 3) * 4;
  const int dd = t >> 4, cb = (t & 15) * 4;
  const float* arow = table + (size_t)idx_s[mr] * D + c4;
  const float* brow = w1 + (size_t)dd * H + h0 + cb;

  float acc[4][4] = {{0.f}};

  float4 av = *(const float4*)(arow);
  float4 bv = *(const float4*)(brow);
  {
    float a[4] = {av.x, av.y, av.z, av.w};
    #pragma unroll
    for (int j = 0; j < 4; ++j) As[0][c4 + j][mr] = a[j];
    *(float4*)&Bs[0][dd][cb] = bv;
  }
  __syncthreads();

  for (int kt = 0; kt < D / BK2; ++kt) {
    const int cur = kt & 1;
    if (kt < D / BK2 - 1) {
      av = *(const float4*)(arow + (kt + 1) * BK2);
      bv = *(const float4*)(brow + (size_t)(kt + 1) * BK2 * H);
    }
    #pragma unroll
    for (int kk = 0; kk < BK2; ++kk) {
      float4 a4 = *(const float4*)&As[cur][kk][ty * 4];
      float4 b4 = *(const float4*)&Bs[cur][kk][tx * 4];
      float a[4] = {a4.x,a4.y,a4.z,a4.w}, b[4] = {b4.x,b4.y,b4.z,b4.w};
      #pragma unroll
      for (int i = 0; i < 4; ++i)
        #pragma unroll
        for (int j = 0; j < 4; ++j) acc[i][j] += a[i] * b[j];
    }
    if (kt < D / BK2 - 1) {
      float a[4] = {av.x, av.y, av.z, av.w};
      #pragma unroll
      for (int j = 0; j < 4; ++j) As[cur ^ 1][c4 + j][mr] = a[j];
      *(float4*)&Bs[cur ^ 1][dd][cb] = bv;
    }
    __syncthreads();
  }

  #pragma unroll
  for (int i = 0; i < 4; ++i) {
    const int m = m0 + ty * 4 + i;
    float v0 = acc[i][0] + b1[h0 + tx * 4 + 0];
    float v1 = acc[i][1] + b1[h0 + tx * 4 + 1];
    float v2 = acc[i][2] + b1[h0 + tx * 4 + 2];
    float v3 = acc[i][3] + b1[h0 + tx * 4 + 3];
    float4 o;
    o.x = v0 > 0.f ? v0 : 0.f;
    o.y = v1 > 0.f ? v1 : 0.f;
    o.z = v2 > 0.f ? v2 : 0.f;
    o.w = v3 > 0.f ? v3 : 0.f;
    *(float4*)(h1 + (size_t)m * H + h0 + tx * 4) = o;
  }
}

// ---------------- init d_out with biases (clears 0xAA poison) ----------
__global__ void init_out_kernel(const float* __restrict__ b2u,
                                const float* __restrict__ b2s,
                                float* __restrict__ out)
{
  const int i = blockIdx.x * blockDim.x + threadIdx.x;
  if (i < M * D) out[i] = b2u[i & (D - 1)];
  else           out[i] = b2s[i & (D - 1)];
}

// ---------------- Kernel B2: [mu|logstd] += h1 @ [w2u|w2s]  (split-K=4) ----
constexpr int KSPLIT = 4;

__global__ __launch_bounds__(256) void mlp2_kernel(
    const float* __restrict__ h1,
    const float* __restrict__ w2u, const float* __restrict__ w2s,
    float* __restrict__ out)
{
  __shared__ float As[2][BK2][BM2];
  __shared__ float Bs[2][BK2][BN2];

  const int t  = threadIdx.x;
  const int tx = t & 15, ty = t >> 4;
  const int n0 = blockIdx.x * BN2;           // over [w2u|w2s] concat (2*D wide)
  const int m0 = blockIdx.y * BM2;
  const int k0 = blockIdx.z * (H / KSPLIT);  // 512-wide K chunk

  const float* Wn = (n0 < D) ? w2u : w2s;
  const int col0 = n0 & (D - 1);

  const int mr = t >> 2, c4 = (t & 3) * 4;
  const int dd = t >> 4, cb = (t & 15) * 4;
  const float* arow = h1 + (size_t)(m0 + mr) * H + k0 + c4;
  const float* brow = Wn + (size_t)(k0 + dd) * D + col0 + cb;

  float acc[4][4] = {{0.f}};
  constexpr int NITER = (H / KSPLIT) / BK2;  // 32

  float4 av = *(const float4*)(arow);
  float4 bv = *(const float4*)(brow);
  {
    float a[4] = {av.x, av.y, av.z, av.w};
    #pragma unroll
    for (int j = 0; j < 4; ++j) As[0][c4 + j][mr] = a[j];
    *(float4*)&Bs[0][dd][cb] = bv;
  }
  __syncthreads();

  for (int kt = 0; kt < NITER; ++kt) {
    const int cur = kt & 1;
    if (kt < NITER - 1) {
      av = *(const float4*)(arow + (kt + 1) * BK2);
      bv = *(const float4*)(brow + (size_t)(kt + 1) * BK2 * D);
    }
    #pragma unroll
    for (int kk = 0; kk < BK2; ++kk) {
      float4 a4 = *(const float4*)&As[cur][kk][ty * 4];
      float4 b4 = *(const float4*)&Bs[cur][kk][tx * 4];
      float a[4] = {a4.x,a4.y,a4.z,a4.w}, b[4] = {b4.x,b4.y,b4.z,b4.w};
      #pragma unroll
      for (int i = 0; i < 4; ++i)
        #pragma unroll
        for (int j = 0; j < 4; ++j) acc[i][j] += a[i] * b[j];
    }
    if (kt < NITER - 1) {
      float a[4] = {av.x, av.y, av.z, av.w};
      #pragma unroll
      for (int j = 0; j < 4; ++j) As[cur ^ 1][c4 + j][mr] = a[j];
      *(float4*)&Bs[cur ^ 1][dd][cb] = bv;
    }
    __syncthreads();
  }

  #pragma unroll
  for (int i = 0; i < 4; ++i) {
    const int m = m0 + ty * 4 + i;
    const int c = col0 + tx * 4;
    float* dst = (n0 < D) ? (out + (size_t)m * D + c)
                          : (out + (size_t)(M * D) + (size_t)m * D + c);
    #pragma unroll
    for (int j = 0; j < 4; ++j) atomicAdd(dst + j, acc[i][j]);
  }
}

extern "C" void kernel_launch(void* const* d_in, const int* in_sizes, int n_in,
                              void* d_out, int out_size, void* d_ws, size_t ws_size,
                              hipStream_t stream)
{
  const float* codes = (const float*)d_in[0];
  const float* table = (const float*)d_in[1];
  const float* w1    = (const float*)d_in[2];
  const float* b1    = (const float*)d_in[3];
  const float* w2u   = (const float*)d_in[4];
  const float* b2u   = (const float*)d_in[5];
  const float* w2s   = (const float*)d_in[6];
  const float* b2s   = (const float*)d_in[7];
  float* out = (float*)d_out;

  unsigned short* chi = (unsigned short*)((char*)d_ws + WS_CODES_HI);
  unsigned long long* keys = (unsigned long long*)((char*)d_ws + WS_KEYS);
  unsigned* final_idx = (unsigned*)((char*)d_ws + WS_IDX);
  float* h1 = (float*)((char*)d_ws + WS_H1);

  convert_codes_kernel<<<(M * D) / 256, 256, 0, stream>>>(codes, chi);

  dist_mfma_kernel<<<NBLK, 512, 0, stream>>>(table, chi, keys);

  merge_rescore_kernel<<<M, 256, 0, stream>>>(keys, codes, table, final_idx);

  dim3 gB1(H / BN2, M / BM2);
  mlp1_kernel<<<gB1, 256, 0, stream>>>(final_idx, table, w1, b1, h1);

  init_out_kernel<<<(2 * M * D) / 256, 256, 0, stream>>>(b2u, b2s, out);

  dim3 gB2((2 * D) / BN2, M / BM2, KSPLIT);
  mlp2_kernel<<<gB2, 256, 0, stream>>>(h1, w2u, w2s, out);
}